// Round 2
// baseline (1455.943 us; speedup 1.0000x reference)
//
#include <hip/hip_runtime.h>
#include <hip/hip_bf16.h>
#include <stdint.h>

typedef unsigned short u16;
typedef unsigned int u32;

#define F1 274625   // 65^3
#define IJ1 4225    // 65^2

typedef float v4f __attribute__((ext_vector_type(4)));
typedef __bf16 v8bf __attribute__((ext_vector_type(8)));

__device__ __forceinline__ float lof(u32 u) { union { u32 u; float f; } c; c.u = u << 16; return c.f; }
__device__ __forceinline__ float hif(u32 u) { union { u32 u; float f; } c; c.u = u & 0xffff0000u; return c.f; }
__device__ __forceinline__ u16 f2bf(float f) {
  union { float f; u32 u; } c; c.f = f;
  u32 r = (c.u >> 16) & 1u;
  return (u16)((c.u + 0x7fffu + r) >> 16);
}
// pack two f32 (as bit patterns) -> two bf16 in one u32 (element a = low half)
__device__ __forceinline__ u32 pkbf(u32 a, u32 b) {
  union { float f; u32 u; } ca, cb; ca.u = a; cb.u = b;
  __hip_bfloat162 h = __float22bfloat162_rn(make_float2(ca.f, cb.f));
  union { __hip_bfloat162 h; u32 u; } c; c.h = h; return c.u;
}

// ---------------- K0: transpose vec1/2/3 [512][64] f32 -> xT [3][64][512] f32
__global__ void __launch_bounds__(256) k0_transpose(const float* __restrict__ v1,
    const float* __restrict__ v2, const float* __restrict__ v3, float* __restrict__ xT) {
  int g = blockIdx.x * 256 + threadIdx.x;
  if (g >= 3 * 64 * 512) return;
  int t = g >> 15, r = g & 32767;
  int d = r >> 9, b = r & 511;
  const float* v = (t == 0) ? v1 : ((t == 1) ? v2 : v3);
  xT[g] = v[b * 64 + d];
}

// ---------------- K1: bilinear partial sums -> zsum [3][64][512] f32 (atomic)
// z_t[b,o] = sum_i x1[b,i] * sum_j zw_t[o,i,j] * vec3[b,j]   (x1 = vec1, vec2, vec1)
__global__ void __launch_bounds__(256) k1_bilinear(
    const float* __restrict__ zw1, const float* __restrict__ zw2, const float* __restrict__ zw3,
    const float* __restrict__ xT, float* __restrict__ zsum) {
  int bid = blockIdx.x;                 // 768 = t*256 + o*4 + bh*2 + ih
  int ih = bid & 1, bh = (bid >> 1) & 1;
  int o = (bid >> 2) & 63, t = bid >> 8;
  int b = bh * 256 + threadIdx.x;
  const float* zw = (t == 0) ? zw1 : ((t == 1) ? zw2 : zw3);
  const float* xiT = xT + ((t == 1) ? 32768 : 0);  // branches 0,2 use vec1; 1 uses vec2
  const float* x3T = xT + 65536;                   // j-side is always vec3
  float x3r[64];
#pragma unroll
  for (int j = 0; j < 64; ++j) x3r[j] = x3T[j * 512 + b];
  const float4* w4 = (const float4*)(zw + o * 4096);
  float acc = 0.f;
  int i0 = ih * 32;
#pragma unroll 2
  for (int i = i0; i < i0 + 32; ++i) {
    float xi = xiT[i * 512 + b];
    float s = 0.f;
#pragma unroll
    for (int q = 0; q < 16; ++q) {
      float4 w = w4[i * 16 + q];   // uniform index -> scalar loads
      s += w.x * x3r[q*4+0] + w.y * x3r[q*4+1] + w.z * x3r[q*4+2] + w.w * x3r[q*4+3];
    }
    acc += xi * s;
  }
  atomicAdd(&zsum[t * 32768 + o * 512 + b], acc);
}

// ---------------- K2: per-branch h/o layers -> oT f32 [3][65][512], o3row bf16 [512][72]
__global__ void __launch_bounds__(256) k2_branch(
    const float* __restrict__ hw1, const float* __restrict__ hb1,
    const float* __restrict__ ow1, const float* __restrict__ ob1,
    const float* __restrict__ hw2, const float* __restrict__ hb2,
    const float* __restrict__ ow2, const float* __restrict__ ob2,
    const float* __restrict__ hw3, const float* __restrict__ hb3,
    const float* __restrict__ ow3, const float* __restrict__ ob3,
    const float* __restrict__ zb1, const float* __restrict__ zb2, const float* __restrict__ zb3,
    const float* __restrict__ xT, const float* __restrict__ zsum,
    float* __restrict__ oT, u16* __restrict__ o3row) {
  int t = blockIdx.x >> 3, bc = blockIdx.x & 7;   // 24 blocks
  int lane = threadIdx.x & 63;
  int w = __builtin_amdgcn_readfirstlane((int)(threadIdx.x >> 6));
  int b = bc * 64 + lane;
  const float* hw = (t==0)?hw1:((t==1)?hw2:hw3);
  const float* hb = (t==0)?hb1:((t==1)?hb2:hb3);
  const float* ow = (t==0)?ow1:((t==1)?ow2:ow3);
  const float* ob = (t==0)?ob1:((t==1)?ob2:ob3);
  const float* zb = (t==0)?zb1:((t==1)?zb2:zb3);
  const float* xtT = xT + t * 32768;
  const float4* hw4 = (const float4*)hw;
  const float4* ow4 = (const float4*)ow;
  __shared__ float gT[64][68];
  float xr[64];
#pragma unroll
  for (int k = 0; k < 64; ++k) xr[k] = xtT[k * 512 + b];
#pragma unroll
  for (int ii = 0; ii < 16; ii += 4) {
    float gv[4];
#pragma unroll
    for (int q = 0; q < 4; ++q) {
      int i = w * 16 + ii + q;
      float a = hb[i];
#pragma unroll
      for (int kq = 0; kq < 16; ++kq) {
        float4 h4 = hw4[i * 16 + kq];
        a += h4.x * xr[kq*4+0] + h4.y * xr[kq*4+1] + h4.z * xr[kq*4+2] + h4.w * xr[kq*4+3];
      }
      float hv = fmaxf(a, 0.f);
      float z = zsum[t * 32768 + i * 512 + b] + zb[i];
      float sg = 1.f / (1.f + __expf(-z));
      gv[q] = sg * hv;
    }
    *(float4*)&gT[lane][w * 16 + ii] = make_float4(gv[0], gv[1], gv[2], gv[3]);
  }
  __syncthreads();
  float gr[64];
#pragma unroll
  for (int k = 0; k < 64; k += 4) {
    float4 g4 = *(const float4*)&gT[lane][k];
    gr[k] = g4.x; gr[k+1] = g4.y; gr[k+2] = g4.z; gr[k+3] = g4.w;
  }
#pragma unroll
  for (int ii = 0; ii < 16; ++ii) {
    int oo = w * 16 + ii;
    float a = ob[oo];
#pragma unroll
    for (int kq = 0; kq < 16; ++kq) {
      float4 o4 = ow4[oo * 16 + kq];
      a += o4.x * gr[kq*4+0] + o4.y * gr[kq*4+1] + o4.z * gr[kq*4+2] + o4.w * gr[kq*4+3];
    }
    float ov = fmaxf(a, 0.f);
    oT[(t * 65 + oo) * 512 + b] = ov;
    if (t == 2) o3row[b * 72 + oo] = f2bf(ov);
  }
  if (w == 0) oT[(t * 65 + 64) * 512 + b] = 1.f;       // ones column
  if (t == 2 && w == 1) {
    uint4 ones = make_uint4(0x3F80u, 0u, 0u, 0u);      // bf16 1.0, then zero pad
    *(uint4*)&o3row[b * 72 + 64] = ones;
  }
}

// ---------------- K3: o12b bf16 [4225][512] = o1[b,i]*o2[b,j]
__global__ void __launch_bounds__(256) k3_o12(const float* __restrict__ oT, u16* __restrict__ o12b) {
  int total = IJ1 * 512;
  for (int g = blockIdx.x * 256 + threadIdx.x; g < total; g += gridDim.x * 256) {
    int ij = g >> 9, b = g & 511;
    int i = ij / 65, j = ij - i * 65;
    o12b[g] = f2bf(oT[i * 512 + b] * oT[(65 + j) * 512 + b]);
  }
}

// ---------------- K4: main GEMM: accum[b,o] (+=) sum_f o123[b,f]*W1[o,f]
// W is f32; converted to bf16 during LDS staging (single pass over 281 MB).
__global__ void __launch_bounds__(256, 2) k4_gemm(
    const float* __restrict__ W, const u16* __restrict__ o3row,
    const u16* __restrict__ o12b, float* __restrict__ accum) {
  __shared__ u16 o3r[128 * 72];
  __shared__ u16 Bs[128 * 72];
  __shared__ u16 o12s[128];
  int bid = blockIdx.x;                         // 512 = sK*8 + mn  (same sK adjacent)
  int sK = bid >> 3, mn = bid & 7;
  int mbase = (mn >> 1) * 128, nbase = (mn & 1) * 128;
  int ij0 = (sK * IJ1) >> 6, ij1 = ((sK + 1) * IJ1) >> 6;
  int tid = threadIdx.x;
  {  // persistent o3 rows: contiguous copy [128][72] bf16
    const uint4* src = (const uint4*)(o3row + mbase * 72);
    uint4* dst = (uint4*)o3r;
    for (int u = tid; u < (128 * 72) / 8; u += 256) dst[u] = src[u];
  }
  int lane = tid & 63;
  int wid = __builtin_amdgcn_readfirstlane(tid >> 6);
  int wm = wid >> 1, wn = wid & 1;
  int lrow = lane & 15, lkg = lane >> 4;
  int rr_ = tid >> 1, hh = tid & 1;
  long growBase = (long)(nbase + rr_) * F1;     // f32 element index of row start
  int aoff0 = (wm * 64 + lrow) * 72 + lkg * 8;
  int boff0 = (wn * 64 + lrow) * 72 + lkg * 8;
  v4f acc[16] = {};
  __syncthreads();
  for (int ij = ij0; ij < ij1; ++ij) {
    {  // stage W rows [o, ij*65 .. +65): f32 loads, dword realign, cvt->bf16
      long g0 = growBase + (long)ij * 65;
      int s4 = (int)(g0 & 3);
      const uint4* Wq = (const uint4*)W;
      long u4d = (g0 >> 2) + (long)hh * 8;
      uint4 q0 = Wq[u4d + 0], q1 = Wq[u4d + 1], q2 = Wq[u4d + 2];
      uint4 q3 = Wq[u4d + 3], q4 = Wq[u4d + 4], q5 = Wq[u4d + 5];
      uint4 q6 = Wq[u4d + 6], q7 = Wq[u4d + 7], q8 = Wq[u4d + 8];
      u32 L[36] = {q0.x,q0.y,q0.z,q0.w, q1.x,q1.y,q1.z,q1.w, q2.x,q2.y,q2.z,q2.w,
                   q3.x,q3.y,q3.z,q3.w, q4.x,q4.y,q4.z,q4.w, q5.x,q5.y,q5.z,q5.w,
                   q6.x,q6.y,q6.z,q6.w, q7.x,q7.y,q7.z,q7.w, q8.x,q8.y,q8.z,q8.w};
      u32 A_[34], Bv[33];
#pragma unroll
      for (int j = 0; j < 34; ++j) A_[j] = (s4 & 2) ? L[j + 2] : L[j];
#pragma unroll
      for (int j = 0; j < 33; ++j) Bv[j] = (s4 & 1) ? A_[j + 1] : A_[j];
      u32 Pk[16];
#pragma unroll
      for (int c = 0; c < 16; ++c) Pk[c] = pkbf(Bv[2 * c], Bv[2 * c + 1]);
      u16* bp = &Bs[rr_ * 72 + hh * 32];
      *(uint4*)(bp + 0)  = make_uint4(Pk[0],  Pk[1],  Pk[2],  Pk[3]);
      *(uint4*)(bp + 8)  = make_uint4(Pk[4],  Pk[5],  Pk[6],  Pk[7]);
      *(uint4*)(bp + 16) = make_uint4(Pk[8],  Pk[9],  Pk[10], Pk[11]);
      *(uint4*)(bp + 24) = make_uint4(Pk[12], Pk[13], Pk[14], Pk[15]);
      if (hh) Bs[rr_ * 72 + 64] = (u16)(pkbf(Bv[32], Bv[32]) & 0xffffu); // col 64
    }
    if (tid < 16)
      ((uint4*)o12s)[tid] = ((const uint4*)(o12b + ((long)ij << 9) + mbase))[tid];
    __syncthreads();
    v4f P[16] = {};
#pragma unroll
    for (int kk = 0; kk < 64; kk += 32) {
      v8bf af[4], bfr[4];
#pragma unroll
      for (int t2 = 0; t2 < 4; ++t2) {
        af[t2]  = *(const v8bf*)&o3r[aoff0 + t2 * (16 * 72) + kk];
        bfr[t2] = *(const v8bf*)&Bs [boff0 + t2 * (16 * 72) + kk];
      }
#pragma unroll
      for (int t2 = 0; t2 < 4; ++t2)
#pragma unroll
        for (int u2 = 0; u2 < 4; ++u2)
          P[t2 * 4 + u2] = __builtin_amdgcn_mfma_f32_16x16x32_bf16(af[t2], bfr[u2], P[t2 * 4 + u2], 0, 0, 0);
    }
    float vv[4];
#pragma unroll
    for (int u2 = 0; u2 < 4; ++u2) vv[u2] = lof((u32)Bs[(wn * 64 + u2 * 16 + lrow) * 72 + 64]);
    float sv[4][4];
#pragma unroll
    for (int t2 = 0; t2 < 4; ++t2) {
      uint2 pr = *(const uint2*)&o12s[wm * 64 + t2 * 16 + lkg * 4];
      sv[t2][0] = lof(pr.x); sv[t2][1] = hif(pr.x);
      sv[t2][2] = lof(pr.y); sv[t2][3] = hif(pr.y);
    }
#pragma unroll
    for (int t2 = 0; t2 < 4; ++t2)
#pragma unroll
      for (int u2 = 0; u2 < 4; ++u2)
#pragma unroll
        for (int e = 0; e < 4; ++e)
          acc[t2 * 4 + u2][e] += sv[t2][e] * (P[t2 * 4 + u2][e] + vv[u2]);
    __syncthreads();
  }
#pragma unroll
  for (int t2 = 0; t2 < 4; ++t2) {
    int gb0 = mbase + wm * 64 + t2 * 16 + lkg * 4;
#pragma unroll
    for (int u2 = 0; u2 < 4; ++u2) {
      int go = nbase + wn * 64 + u2 * 16 + lrow;
#pragma unroll
      for (int e = 0; e < 4; ++e)
        atomicAdd(&accum[(gb0 + e) * 256 + go], acc[t2 * 4 + u2][e]);
    }
  }
}

// ---------------- K5: enc2 with relu(enc1)+skip concat -> out f32 [512][256]
__global__ void __launch_bounds__(256) k5_enc2(
    const float* __restrict__ accum, const float* __restrict__ oT,
    const float* __restrict__ enc1b, const float* __restrict__ w2,
    const float* __restrict__ enc2b, float* __restrict__ outp) {
  int bg = blockIdx.x >> 3, og = blockIdx.x & 7;   // 64 blocks
  int lane = threadIdx.x & 63;
  int w = __builtin_amdgcn_readfirstlane((int)(threadIdx.x >> 6));
  int b = bg * 64 + lane;
  int obase = og * 32 + w * 8;
  float a8[8];
#pragma unroll
  for (int q = 0; q < 8; ++q) a8[q] = enc2b[obase + q];
  for (int c = 0; c < 256; ++c) {
    float x = fmaxf(accum[b * 256 + c] + enc1b[c], 0.f);
#pragma unroll
    for (int q = 0; q < 8; ++q) a8[q] += w2[(obase + q) * 451 + c] * x;
  }
  for (int e = 0; e < 195; ++e) {
    float x = oT[e * 512 + b];   // rows: o1(65), o2(65), o3(65) — matches concat order
#pragma unroll
    for (int q = 0; q < 8; ++q) a8[q] += w2[(obase + q) * 451 + 256 + e] * x;
  }
#pragma unroll
  for (int q = 0; q < 8; ++q) outp[b * 256 + obase + q] = fmaxf(a8[q], 0.f);
}

extern "C" void kernel_launch(void* const* d_in, const int* in_sizes, int n_in,
                              void* d_out, int out_size, void* d_ws, size_t ws_size,
                              hipStream_t stream) {
  const float* vec1 = (const float*)d_in[0];
  const float* vec2 = (const float*)d_in[1];
  const float* vec3 = (const float*)d_in[2];
  const float* h1w = (const float*)d_in[3];  const float* h1b = (const float*)d_in[4];
  const float* z1w = (const float*)d_in[5];  const float* z1b = (const float*)d_in[6];
  const float* o1w = (const float*)d_in[7];  const float* o1b = (const float*)d_in[8];
  const float* h2w = (const float*)d_in[9];  const float* h2b = (const float*)d_in[10];
  const float* z2w = (const float*)d_in[11]; const float* z2b = (const float*)d_in[12];
  const float* o2w = (const float*)d_in[13]; const float* o2b = (const float*)d_in[14];
  const float* h3w = (const float*)d_in[15]; const float* h3b = (const float*)d_in[16];
  const float* z3w = (const float*)d_in[17]; const float* z3b = (const float*)d_in[18];
  const float* o3w = (const float*)d_in[19]; const float* o3b = (const float*)d_in[20];
  const float* e1w = (const float*)d_in[21]; const float* e1b = (const float*)d_in[22];
  const float* e2w = (const float*)d_in[23]; const float* e2b = (const float*)d_in[24];

  char* ws = (char*)d_ws;
  float* accum = (float*)(ws + 0);              // 512*256*4 = 524288
  float* oT    = (float*)(ws + 524288);         // 3*65*512*4 = 399360
  u16* o3row   = (u16*)  (ws + 923648);         // 512*72*2   = 73728
  u16* o12b    = (u16*)  (ws + 997376);         // 4225*512*2 = 4326400
  float* xT    = (float*)(ws + 5323776);        // 3*64*512*4 = 393216
  float* zsum  = (float*)(ws + 5716992);        // 3*64*512*4 = 393216

  hipMemsetAsync(accum, 0, 524288, stream);
  hipMemsetAsync(zsum, 0, 393216, stream);

  hipLaunchKernelGGL(k0_transpose, dim3(384), dim3(256), 0, stream, vec1, vec2, vec3, xT);
  hipLaunchKernelGGL(k1_bilinear, dim3(768), dim3(256), 0, stream, z1w, z2w, z3w, xT, zsum);
  hipLaunchKernelGGL(k2_branch, dim3(24), dim3(256), 0, stream,
                     h1w, h1b, o1w, o1b, h2w, h2b, o2w, o2b, h3w, h3b, o3w, o3b,
                     z1b, z2b, z3b, xT, zsum, oT, o3row);
  hipLaunchKernelGGL(k3_o12, dim3(2048), dim3(256), 0, stream, oT, o12b);
  hipLaunchKernelGGL(k4_gemm, dim3(512), dim3(256), 0, stream, e1w, o3row, o12b, accum);
  hipLaunchKernelGGL(k5_enc2, dim3(64), dim3(256), 0, stream, accum, oT, e1b, e2w, e2b,
                     (float*)d_out);
}